// Round 14
// baseline (2473.417 us; speedup 1.0000x reference)
//
#include <hip/hip_runtime.h>

#define HID 15
#define NG  60      // 4*HID
#define DIM 64
#define T2  2048
#define NLAY 4
#define BSZ 512
#define DG  8       // supersteps per barrier group (layer skew depth)
#define RS  16      // h-ring slots = 2*DG

// bf16 RNE rounding — PROVEN bit-trick (rounds 6/7). v_cvt_pk_bf16_f32
// produced NaNs twice (even battery-guarded) — do not revisit.
__device__ __forceinline__ float bfr(float x) {
    unsigned u = __float_as_uint(x);
    u = (u + 0x7FFFu + ((u >> 16) & 1u)) & 0xFFFF0000u;
    return __uint_as_float(u);
}
// one bf16-rounded multiply-accumulate term: acc = bf(acc + bf(a*b))
#define CH(acc, a, b) acc = bfr(acc + bfr((a) * (b)))

__device__ __forceinline__ float tanh_np(float z) {
    const float e = __expf(-2.0f * z);
    return bfr((1.0f - e) / (1.0f + e));
}
__device__ __forceinline__ float sig_np(float z) {
    const float e   = bfr(__expf(-z));
    const float den = bfr(1.0f + e);
    return bfr(1.0f / den);
}
__device__ __forceinline__ float b2f(unsigned b) {
    return __uint_as_float(b << 16);
}
// intra-quad broadcast via DPP quad_perm (exact lane move, ~VALU latency)
#define QB(x, CTRL) __uint_as_float((unsigned)__builtin_amdgcn_mov_dpp( \
        (int)__float_as_uint(x), (CTRL), 0xF, 0xF, false))

// ============ Phase 1: layer-0 projection, 2 rows per wave (R13) ============
__global__ __launch_bounds__(256, 1)
void proj0(const float* __restrict__ emb,
           const int*   __restrict__ lengths,
           const float* __restrict__ Wih0,
           unsigned short* __restrict__ pa)
{
    const int wave = threadIdx.x >> 6;
    const int lane = threadIdx.x & 63;
    const int g    = (lane < NG) ? lane : (NG - 1);

    __shared__ __align__(16) float xrow[4][2][64];

    float wx[DIM];
    #pragma unroll
    for (int q = 0; q < 16; ++q) {
        float4 w = *(const float4*)(Wih0 + g*DIM + 4*q);
        wx[4*q+0] = bfr(w.x); wx[4*q+1] = bfr(w.y);
        wx[4*q+2] = bfr(w.z); wx[4*q+3] = bfr(w.w);
    }

    const int npairs = (BSZ * T2) / 2;
    const int stride = gridDim.x * 4;
    const int p0     = blockIdx.x * 4 + wave;

    float xr0 = 0.0f, xr1 = 0.0f;
    if (p0 < npairs) {
        xr0 = emb[(size_t)(2*p0)     * DIM + lane];
        xr1 = emb[(size_t)(2*p0 + 1) * DIM + lane];
    }

    for (int p = p0; p < npairs; p += stride) {
        const int pn = p + stride;
        float xn0 = 0.0f, xn1 = 0.0f;
        if (pn < npairs) {
            xn0 = emb[(size_t)(2*pn)     * DIM + lane];
            xn1 = emb[(size_t)(2*pn + 1) * DIM + lane];
        }

        const int r   = 2 * p;
        const int b   = r >> 11;
        const int t   = r & (T2 - 1);
        const int len = lengths[b];

        if (t < len) {
            xrow[wave][0][lane] = bfr(xr0);
            xrow[wave][1][lane] = bfr(xr1);
            const float4* xv0 = (const float4*)xrow[wave][0];
            const float4* xv1 = (const float4*)xrow[wave][1];
            float a0 = 0.0f, a1 = 0.0f;
            #pragma unroll
            for (int q = 0; q < 16; ++q) {
                float4 u = xv0[q]; float4 v = xv1[q];
                CH(a0, u.x, wx[4*q+0]); CH(a1, v.x, wx[4*q+0]);
                CH(a0, u.y, wx[4*q+1]); CH(a1, v.y, wx[4*q+1]);
                CH(a0, u.z, wx[4*q+2]); CH(a1, v.z, wx[4*q+2]);
                CH(a0, u.w, wx[4*q+3]); CH(a1, v.w, wx[4*q+3]);
            }
            if (lane < NG) {
                pa[(size_t)r * NG + g] = (unsigned short)(__float_as_uint(a0) >> 16);
                if (t + 1 < len)
                    pa[(size_t)(r + 1) * NG + g] = (unsigned short)(__float_as_uint(a1) >> 16);
            }
        }
        xr0 = xn0; xr1 = xn1;
    }
}

// ====== Phase 2: deep-ring pipeline, quad gate layout, DPP combine ======
// Lane = 4*j + k holds gate k (i,f,g,o) of hidden j: gate row = k*15+j.
// Gate combine = 4 DPP quad broadcasts (was 3 ds_bpermute ~330cy).
// Activation: ONE exp + both exact tails + select (was 2 exec-masked paths).
// ain(t+1) chain computed interleaved with a_rec(t) (ring data for the whole
// group is published one barrier ago — R13 skew). Per-gate op sequences are
// identical to rounds 6/7 -> bit-identical output.
__global__ __launch_bounds__(256, 1)
void lstm4_pipe(const int* __restrict__ lengths,
                const unsigned short* __restrict__ pa,
                const float* __restrict__ Wihr,
                const float* __restrict__ Whh,
                const float* __restrict__ bih,
                const float* __restrict__ bhh,
                float* __restrict__ out)
{
    const int s    = blockIdx.x;
    const int wave = threadIdx.x >> 6;     // = layer index l
    const int lane = threadIdx.x & 63;
    const int k    = lane & 3;             // gate (i,f,g,o)
    const int jq   = lane >> 2;            // hidden index (quad)
    const int j_c  = (jq < HID) ? jq : (HID - 1);   // clamp quad 15
    const int row  = k * HID + j_c;        // PyTorch gate-row index

    __shared__ __align__(16) float ring[NLAY-1][RS][16];

    // zero-init ring (incl. pad col 15 — hv[15]*wi[15] must be 0*0)
    for (int i = threadIdx.x; i < (NLAY-1)*RS*16; i += 256)
        ((float*)ring)[i] = 0.0f;

    const int l = wave;
    float wr[HID], wi[HID];
    #pragma unroll
    for (int h = 0; h < HID; ++h) wr[h] = bfr(Whh[(l*NG + row)*HID + h]);
    if (l > 0) {
        #pragma unroll
        for (int h = 0; h < HID; ++h) wi[h] = bfr(Wihr[((l-1)*NG + row)*HID + h]);
    } else {
        #pragma unroll
        for (int h = 0; h < HID; ++h) wi[h] = 0.0f;
    }
    const float bias_ = bfr(bfr(bih[l*NG + row]) + bfr(bhh[l*NG + row]));

    int len = lengths[s];
    len = len < 1 ? 1 : (len > T2 ? T2 : len);
    const unsigned short* pas = pa + (size_t)s * T2 * NG;

    float c_ = 0.0f;
    float hs[HID];
    #pragma unroll
    for (int h = 0; h < HID; ++h) hs[h] = 0.0f;

    unsigned pan_c[DG], pan_n[DG];
    if (l == 0) {
        #pragma unroll
        for (int d = 0; d < DG; ++d) {
            const int tt = (d < len) ? d : (len - 1);
            pan_n[d] = pas[(size_t)tt * NG + row];
        }
    }

    const bool tg  = (k == 2);
    const int ngrp = (len + DG - 1) / DG;
    const int G    = ngrp + NLAY - 1;

    __syncthreads();                         // ring init visible

    for (int grp = 0; grp < G; ++grp) {
        const int myg = grp - l;
        if (myg >= 0 && myg < ngrp) {        // wave-uniform
            const int t0 = myg * DG;

            if (l == 0) {                    // rotate + prefetch next group
                #pragma unroll
                for (int d = 0; d < DG; ++d) pan_c[d] = pan_n[d];
                #pragma unroll
                for (int d = 0; d < DG; ++d) {
                    int tt = t0 + DG + d; tt = (tt < len) ? tt : (len - 1);
                    pan_n[d] = pas[(size_t)tt * NG + row];
                }
            }

            // prologue: ain for t0
            float ain_cur = 0.0f;
            if (l == 0) {
                ain_cur = b2f(pan_c[0]);
            } else {
                float hv[16];
                const float4* hp = (const float4*)ring[l-1][t0 & (RS-1)];
                *(float4*)&hv[0] = hp[0]; *(float4*)&hv[4]  = hp[1];
                *(float4*)&hv[8] = hp[2]; *(float4*)&hv[12] = hp[3];
                #pragma unroll
                for (int h = 0; h < HID; ++h) CH(ain_cur, hv[h], wi[h]);
            }

            #pragma unroll
            for (int d = 0; d < DG; ++d) {
                const int t = t0 + d;
                if (t < len) {               // wave-uniform
                    // ain(t+1): independent chain, interleaves with a_rec(t)
                    float ain_next = 0.0f;
                    float hvn[16];
                    const bool nx = (d < DG-1) && (t + 1 < len);
                    if (l > 0 && nx) {
                        const float4* hp = (const float4*)ring[l-1][(t+1) & (RS-1)];
                        *(float4*)&hvn[0] = hp[0]; *(float4*)&hvn[4]  = hp[1];
                        *(float4*)&hvn[8] = hp[2]; *(float4*)&hvn[12] = hp[3];
                    }

                    float a_rec = 0.0f;
                    #pragma unroll
                    for (int h = 0; h < HID; ++h) CH(a_rec, hs[h], wr[h]);
                    if (l > 0) {
                        if (nx) {
                            #pragma unroll
                            for (int h = 0; h < HID; ++h) CH(ain_next, hvn[h], wi[h]);
                        }
                    } else {
                        if (d < DG-1) ain_next = b2f(pan_c[d+1]);
                    }

                    const float z = bfr(bfr(ain_cur + a_rec) + bias_);

                    // single-exp activation; exact per-gate op sequences
                    const float arg = tg ? (-2.0f * z) : (-z);
                    const float e   = __expf(arg);
                    const float ea  = bfr(e);              // sig tail
                    const float dns = bfr(1.0f + ea);
                    const float rs_ = bfr(1.0f / dns);
                    const float rt_ = bfr((1.0f - e) / (1.0f + e));  // tanh tail
                    const float a   = tg ? rt_ : rs_;

                    // quad gate combine via DPP broadcasts
                    const float iv = QB(a, 0x00);
                    const float fv = QB(a, 0x55);
                    const float gv = QB(a, 0xAA);
                    const float ov = QB(a, 0xFF);

                    const float cn = bfr(bfr(fv * c_) + bfr(iv * gv));
                    c_ = cn;
                    const float hn = bfr(ov * tanh_np(cn));

                    #pragma unroll
                    for (int h = 0; h < HID; ++h)
                        hs[h] = __uint_as_float(
                            __builtin_amdgcn_readlane(__float_as_uint(hn), 4*h));

                    if (l < NLAY-1 && lane < NG && k == 0)
                        ring[l][t & (RS-1)][jq] = hn;
                    if (l == NLAY-1 && t == len-1 && lane < NG && k == 0)
                        out[s * HID + jq] = hn;

                    ain_cur = ain_next;
                }
            }
        }
        __syncthreads();                     // one barrier per group
    }
}

// ============ Fallback (round-6, passing): used if ws too small ============
__global__ __launch_bounds__(64, 1)
void lstm4_bf16np(const float* __restrict__ emb,
                  const int*   __restrict__ lengths,
                  const float* __restrict__ Wih0,
                  const float* __restrict__ Wihr,
                  const float* __restrict__ Whh,
                  const float* __restrict__ bih,
                  const float* __restrict__ bhh,
                  float* __restrict__ out)
{
    const int s    = blockIdx.x;
    const int lane = threadIdx.x;
    const int g    = (lane < NG) ? lane : (NG - 1);

    __shared__ __align__(16) float x_lds[DIM];
    __shared__ __align__(16) float h_lds[NLAY][16];

    float wx[DIM];
    #pragma unroll
    for (int q = 0; q < DIM/4; ++q) {
        float4 w = *(const float4*)(Wih0 + g*DIM + 4*q);
        wx[4*q+0] = bfr(w.x); wx[4*q+1] = bfr(w.y);
        wx[4*q+2] = bfr(w.z); wx[4*q+3] = bfr(w.w);
    }
    float wr[NLAY][16]; float wi[NLAY-1][16]; float bias[NLAY];
    #pragma unroll
    for (int l = 0; l < NLAY; ++l) {
        #pragma unroll
        for (int j = 0; j < HID; ++j) wr[l][j] = bfr(Whh[(l*NG + g)*HID + j]);
        wr[l][15] = 0.0f;
        bias[l] = bfr(bfr(bih[l*NG + g]) + bfr(bhh[l*NG + g]));
    }
    #pragma unroll
    for (int l = 0; l < NLAY-1; ++l) {
        #pragma unroll
        for (int j = 0; j < HID; ++j) wi[l][j] = bfr(Wihr[(l*NG + g)*HID + j]);
        wi[l][15] = 0.0f;
    }
    if (lane < 16) {
        #pragma unroll
        for (int l = 0; l < NLAY; ++l) h_lds[l][lane] = 0.0f;
    }
    float c[NLAY] = {0.0f, 0.0f, 0.0f, 0.0f};
    int len = lengths[s];
    len = len < 1 ? 1 : (len > T2 ? T2 : len);
    const float* xb = emb + (size_t)s * T2 * DIM;
    x_lds[lane] = bfr(xb[lane]);
    __syncthreads();
    const bool tg = (lane >= 30 && lane < 45);
    const float4* x4 = (const float4*)x_lds;
    float hout = 0.0f;
    for (int t = 0; t < len; ++t) {
        const int tn = (t + 1 < len) ? (t + 1) : t;
        const float xn = bfr(xb[(size_t)tn * DIM + lane]);
        #pragma unroll
        for (int l = 0; l < NLAY; ++l) {
            float a_in = 0.0f;
            if (l == 0) {
                #pragma unroll
                for (int q = 0; q < 16; ++q) {
                    float4 v = x4[q];
                    CH(a_in, v.x, wx[4*q+0]); CH(a_in, v.y, wx[4*q+1]);
                    CH(a_in, v.z, wx[4*q+2]); CH(a_in, v.w, wx[4*q+3]);
                }
            } else {
                const float4* hp = (const float4*)h_lds[l-1];
                float hv[16];
                *(float4*)&hv[0]  = hp[0]; *(float4*)&hv[4]  = hp[1];
                *(float4*)&hv[8]  = hp[2]; *(float4*)&hv[12] = hp[3];
                #pragma unroll
                for (int j = 0; j < HID; ++j) CH(a_in, hv[j], wi[l-1][j]);
            }
            float a_rec = 0.0f;
            {
                const float4* hc = (const float4*)h_lds[l];
                float hv[16];
                *(float4*)&hv[0]  = hc[0]; *(float4*)&hv[4]  = hc[1];
                *(float4*)&hv[8]  = hc[2]; *(float4*)&hv[12] = hc[3];
                #pragma unroll
                for (int j = 0; j < HID; ++j) CH(a_rec, hv[j], wr[l][j]);
            }
            const float z = bfr(bfr(a_in + a_rec) + bias[l]);
            const float a = tg ? tanh_np(z) : sig_np(z);
            const float fv = __shfl(a, (lane + 15) & 63);
            const float gv = __shfl(a, (lane + 30) & 63);
            const float ov = __shfl(a, (lane + 45) & 63);
            const float cn = bfr(bfr(fv * c[l]) + bfr(a * gv));
            c[l] = cn;
            const float hn = bfr(ov * tanh_np(cn));
            if (lane < HID) h_lds[l][lane] = hn;
            if (l == NLAY-1 && t == len-1) hout = hn;
        }
        x_lds[lane] = xn;
    }
    if (lane < HID) out[s * HID + lane] = hout;
}

extern "C" void kernel_launch(void* const* d_in, const int* in_sizes, int n_in,
                              void* d_out, int out_size, void* d_ws, size_t ws_size,
                              hipStream_t stream) {
    const float* emb     = (const float*)d_in[0];
    const int*   lengths = (const int*)  d_in[1];
    const float* Wih0    = (const float*)d_in[2];
    const float* Wihr    = (const float*)d_in[3];
    const float* Whh     = (const float*)d_in[4];
    const float* bih     = (const float*)d_in[5];
    const float* bhh     = (const float*)d_in[6];
    float* out = (float*)d_out;

    const size_t need = (size_t)BSZ * T2 * NG * sizeof(unsigned short);
    if (ws_size >= need) {
        unsigned short* pa = (unsigned short*)d_ws;
        proj0<<<2048, 256, 0, stream>>>(emb, lengths, Wih0, pa);
        lstm4_pipe<<<BSZ, 256, 0, stream>>>(lengths, pa, Wihr, Whh, bih, bhh, out);
    } else {
        lstm4_bf16np<<<BSZ, 64, 0, stream>>>(emb, lengths, Wih0, Wihr, Whh, bih, bhh, out);
    }
}

// Round 15
// 2109.028 us; speedup vs baseline: 1.1728x; 1.1728x over previous
//
#include <hip/hip_runtime.h>
#include <hip/hip_bf16.h>

#define HID 15
#define NG  60      // 4*HID
#define DIM 64
#define T2  2048
#define NLAY 4
#define BSZ 512
#define DG  8       // supersteps per barrier group (layer skew depth)
#define RS  16      // h-ring slots = 2*DG

// bf16 RNE rounding. History: bit-trick (3 dependent int ops) proven rounds
// 6-14. Hand-asm v_cvt_pk_bf16_f32 failed twice (R8/R9 NaN — same-src asm
// variant). THIS round: compiler's __float2bfloat16 (documented RNE, distinct
// known-good codegen, used by HK attn per learn_hip T12/m240). If absmax
// deviates from 0.00390625 -> not RNE -> revert to bit-trick permanently.
__device__ __forceinline__ float bfr(float x) {
    __hip_bfloat16 h = __float2bfloat16(x);
    unsigned short u;
    __builtin_memcpy(&u, &h, 2);
    return __uint_as_float(((unsigned)u) << 16);
}
// one bf16-rounded multiply-accumulate term: acc = bf(acc + bf(a*b))
#define CH(acc, a, b) acc = bfr(acc + bfr((a) * (b)))

__device__ __forceinline__ float tanh_np(float z) {
    const float e = __expf(-2.0f * z);
    return bfr((1.0f - e) / (1.0f + e));
}
__device__ __forceinline__ float sig_np(float z) {
    const float e   = bfr(__expf(-z));
    const float den = bfr(1.0f + e);
    return bfr(1.0f / den);
}
__device__ __forceinline__ float b2f(unsigned b) {
    return __uint_as_float(b << 16);
}

// ============ Phase 1: layer-0 projection, 2 rows per wave (R13) ============
__global__ __launch_bounds__(256, 1)
void proj0(const float* __restrict__ emb,
           const int*   __restrict__ lengths,
           const float* __restrict__ Wih0,
           unsigned short* __restrict__ pa)
{
    const int wave = threadIdx.x >> 6;
    const int lane = threadIdx.x & 63;
    const int g    = (lane < NG) ? lane : (NG - 1);

    __shared__ __align__(16) float xrow[4][2][64];

    float wx[DIM];
    #pragma unroll
    for (int q = 0; q < 16; ++q) {
        float4 w = *(const float4*)(Wih0 + g*DIM + 4*q);
        wx[4*q+0] = bfr(w.x); wx[4*q+1] = bfr(w.y);
        wx[4*q+2] = bfr(w.z); wx[4*q+3] = bfr(w.w);
    }

    const int npairs = (BSZ * T2) / 2;
    const int stride = gridDim.x * 4;
    const int p0     = blockIdx.x * 4 + wave;

    float xr0 = 0.0f, xr1 = 0.0f;
    if (p0 < npairs) {                       // prime pipeline
        xr0 = emb[(size_t)(2*p0)     * DIM + lane];
        xr1 = emb[(size_t)(2*p0 + 1) * DIM + lane];
    }

    for (int p = p0; p < npairs; p += stride) {
        const int pn = p + stride;           // prefetch next pair first
        float xn0 = 0.0f, xn1 = 0.0f;
        if (pn < npairs) {
            xn0 = emb[(size_t)(2*pn)     * DIM + lane];
            xn1 = emb[(size_t)(2*pn + 1) * DIM + lane];
        }

        const int r   = 2 * p;
        const int b   = r >> 11;             // r / T2 (wave-uniform)
        const int t   = r & (T2 - 1);        // even; r+1 is (b, t+1)
        const int len = lengths[b];

        if (t < len) {                       // t>=len implies t+1>=len too
            xrow[wave][0][lane] = bfr(xr0);  // in-wave write->read (lgkmcnt)
            xrow[wave][1][lane] = bfr(xr1);
            const float4* xv0 = (const float4*)xrow[wave][0];
            const float4* xv1 = (const float4*)xrow[wave][1];
            float a0 = 0.0f, a1 = 0.0f;      // two independent chains
            #pragma unroll
            for (int q = 0; q < 16; ++q) {
                float4 u = xv0[q]; float4 v = xv1[q];
                CH(a0, u.x, wx[4*q+0]); CH(a1, v.x, wx[4*q+0]);
                CH(a0, u.y, wx[4*q+1]); CH(a1, v.y, wx[4*q+1]);
                CH(a0, u.z, wx[4*q+2]); CH(a1, v.z, wx[4*q+2]);
                CH(a0, u.w, wx[4*q+3]); CH(a1, v.w, wx[4*q+3]);
            }
            if (lane < NG) {
                pa[(size_t)r * NG + g] = (unsigned short)(__float_as_uint(a0) >> 16);
                if (t + 1 < len)
                    pa[(size_t)(r + 1) * NG + g] = (unsigned short)(__float_as_uint(a1) >> 16);
            }
        }
        xr0 = xn0; xr1 = xn1;
    }
}

// ====== Phase 2: deep-ring layer pipeline (R13 exact structure) ======
// Wave l processes t in [(grp-l)*DG, +DG) during barrier-group grp. h handoff
// via ring[l][t&15]: writer/reader halves disjoint mod 16 -> one barrier per
// group. Per-gate op sequence identical to rounds 6/7 -> bit-identical.
__global__ __launch_bounds__(256, 1)
void lstm4_pipe(const int* __restrict__ lengths,
                const unsigned short* __restrict__ pa,
                const float* __restrict__ Wihr,
                const float* __restrict__ Whh,
                const float* __restrict__ bih,
                const float* __restrict__ bhh,
                float* __restrict__ out)
{
    const int s    = blockIdx.x;
    const int wave = threadIdx.x >> 6;     // = layer index l
    const int lane = threadIdx.x & 63;
    const int g    = (lane < NG) ? lane : (NG - 1);

    __shared__ __align__(16) float ring[NLAY-1][RS][16];   // layers 0..2 publish

    const int l = wave;
    float wr[16], wi[16];
    #pragma unroll
    for (int j = 0; j < HID; ++j) wr[j] = bfr(Whh[(l*NG + g)*HID + j]);
    wr[15] = 0.0f;
    if (l > 0) {
        #pragma unroll
        for (int j = 0; j < HID; ++j) wi[j] = bfr(Wihr[((l-1)*NG + g)*HID + j]);
        wi[15] = 0.0f;
    } else {
        #pragma unroll
        for (int j = 0; j < 16; ++j) wi[j] = 0.0f;
    }
    const float bias_ = bfr(bfr(bih[l*NG + g]) + bfr(bhh[l*NG + g]));

    int len = lengths[s];
    len = len < 1 ? 1 : (len > T2 ? T2 : len);
    const unsigned short* pas = pa + (size_t)s * T2 * NG;

    float c_ = 0.0f;
    float hs[HID];
    #pragma unroll
    for (int j = 0; j < HID; ++j) hs[j] = 0.0f;

    // pa group-prefetch, double-buffered 8-deep (wave 0 only)
    unsigned pan_c[DG], pan_n[DG];
    if (l == 0) {
        #pragma unroll
        for (int d = 0; d < DG; ++d) {
            const int tt = (d < len) ? d : (len - 1);
            pan_n[d] = pas[(size_t)tt * NG + g];
        }
    }

    const bool tg = (lane >= 30 && lane < 45);
    const int ngrp = (len + DG - 1) / DG;    // active groups per wave
    const int G    = ngrp + NLAY - 1;

    for (int grp = 0; grp < G; ++grp) {
        const int myg = grp - l;
        if (myg >= 0 && myg < ngrp) {        // wave-uniform
            const int t0 = myg * DG;

            if (l == 0) {                    // rotate buffers, prefetch next 8
                #pragma unroll
                for (int d = 0; d < DG; ++d) pan_c[d] = pan_n[d];
                #pragma unroll
                for (int d = 0; d < DG; ++d) {
                    int tt = t0 + DG + d; tt = (tt < len) ? tt : (len - 1);
                    pan_n[d] = pas[(size_t)tt * NG + g];
                }
            }

            #pragma unroll
            for (int d = 0; d < DG; ++d) {   // 8 supersteps, NO barrier inside
                const int t = t0 + d;
                if (t < len) {               // wave-uniform
                    float a_in = 0.0f, a_rec = 0.0f;
                    float hv[16];

                    if (l > 0) {             // issue LDS reads early
                        const float4* hp = (const float4*)ring[l-1][t & (RS-1)];
                        *(float4*)&hv[0]  = hp[0]; *(float4*)&hv[4]  = hp[1];
                        *(float4*)&hv[8]  = hp[2]; *(float4*)&hv[12] = hp[3];
                    }

                    #pragma unroll
                    for (int j = 0; j < HID; ++j) CH(a_rec, hs[j], wr[j]);

                    if (l == 0) {
                        a_in = b2f(pan_c[d]);
                    } else {
                        #pragma unroll
                        for (int j = 0; j < HID; ++j) CH(a_in, hv[j], wi[j]);
                    }

                    const float z = bfr(bfr(a_in + a_rec) + bias_);
                    const float a = tg ? tanh_np(z) : sig_np(z);

                    const float fv = __shfl(a, (lane + 15) & 63);
                    const float gv = __shfl(a, (lane + 30) & 63);
                    const float ov = __shfl(a, (lane + 45) & 63);

                    const float cn = bfr(bfr(fv * c_) + bfr(a * gv));
                    c_ = cn;
                    const float hn = bfr(ov * tanh_np(cn));

                    #pragma unroll
                    for (int j = 0; j < HID; ++j)
                        hs[j] = __uint_as_float(__builtin_amdgcn_readlane(__float_as_uint(hn), j));

                    if (l < NLAY - 1 && lane < HID) ring[l][t & (RS-1)][lane] = hn;
                    if (l == NLAY - 1 && t == len - 1 && lane < HID)
                        out[s * HID + lane] = hn;
                }
            }
        }
        __syncthreads();                     // one barrier per group
    }
}

// ============ Fallback (round-6, passing): used if ws too small ============
__global__ __launch_bounds__(64, 1)
void lstm4_bf16np(const float* __restrict__ emb,
                  const int*   __restrict__ lengths,
                  const float* __restrict__ Wih0,
                  const float* __restrict__ Wihr,
                  const float* __restrict__ Whh,
                  const float* __restrict__ bih,
                  const float* __restrict__ bhh,
                  float* __restrict__ out)
{
    const int s    = blockIdx.x;
    const int lane = threadIdx.x;
    const int g    = (lane < NG) ? lane : (NG - 1);

    __shared__ __align__(16) float x_lds[DIM];
    __shared__ __align__(16) float h_lds[NLAY][16];

    float wx[DIM];
    #pragma unroll
    for (int q = 0; q < DIM/4; ++q) {
        float4 w = *(const float4*)(Wih0 + g*DIM + 4*q);
        wx[4*q+0] = bfr(w.x); wx[4*q+1] = bfr(w.y);
        wx[4*q+2] = bfr(w.z); wx[4*q+3] = bfr(w.w);
    }
    float wr[NLAY][16]; float wi[NLAY-1][16]; float bias[NLAY];
    #pragma unroll
    for (int l = 0; l < NLAY; ++l) {
        #pragma unroll
        for (int j = 0; j < HID; ++j) wr[l][j] = bfr(Whh[(l*NG + g)*HID + j]);
        wr[l][15] = 0.0f;
        bias[l] = bfr(bfr(bih[l*NG + g]) + bfr(bhh[l*NG + g]));
    }
    #pragma unroll
    for (int l = 0; l < NLAY-1; ++l) {
        #pragma unroll
        for (int j = 0; j < HID; ++j) wi[l][j] = bfr(Wihr[(l*NG + g)*HID + j]);
        wi[l][15] = 0.0f;
    }
    if (lane < 16) {
        #pragma unroll
        for (int l = 0; l < NLAY; ++l) h_lds[l][lane] = 0.0f;
    }
    float c[NLAY] = {0.0f, 0.0f, 0.0f, 0.0f};
    int len = lengths[s];
    len = len < 1 ? 1 : (len > T2 ? T2 : len);
    const float* xb = emb + (size_t)s * T2 * DIM;
    x_lds[lane] = bfr(xb[lane]);
    __syncthreads();
    const bool tg = (lane >= 30 && lane < 45);
    const float4* x4 = (const float4*)x_lds;
    float hout = 0.0f;
    for (int t = 0; t < len; ++t) {
        const int tn = (t + 1 < len) ? (t + 1) : t;
        const float xn = bfr(xb[(size_t)tn * DIM + lane]);
        #pragma unroll
        for (int l = 0; l < NLAY; ++l) {
            float a_in = 0.0f;
            if (l == 0) {
                #pragma unroll
                for (int q = 0; q < 16; ++q) {
                    float4 v = x4[q];
                    CH(a_in, v.x, wx[4*q+0]); CH(a_in, v.y, wx[4*q+1]);
                    CH(a_in, v.z, wx[4*q+2]); CH(a_in, v.w, wx[4*q+3]);
                }
            } else {
                const float4* hp = (const float4*)h_lds[l-1];
                float hv[16];
                *(float4*)&hv[0]  = hp[0]; *(float4*)&hv[4]  = hp[1];
                *(float4*)&hv[8]  = hp[2]; *(float4*)&hv[12] = hp[3];
                #pragma unroll
                for (int j = 0; j < HID; ++j) CH(a_in, hv[j], wi[l-1][j]);
            }
            float a_rec = 0.0f;
            {
                const float4* hc = (const float4*)h_lds[l];
                float hv[16];
                *(float4*)&hv[0]  = hc[0]; *(float4*)&hv[4]  = hc[1];
                *(float4*)&hv[8]  = hc[2]; *(float4*)&hv[12] = hc[3];
                #pragma unroll
                for (int j = 0; j < HID; ++j) CH(a_rec, hv[j], wr[l][j]);
            }
            const float z = bfr(bfr(a_in + a_rec) + bias[l]);
            const float a = tg ? tanh_np(z) : sig_np(z);
            const float fv = __shfl(a, (lane + 15) & 63);
            const float gv = __shfl(a, (lane + 30) & 63);
            const float ov = __shfl(a, (lane + 45) & 63);
            const float cn = bfr(bfr(fv * c[l]) + bfr(a * gv));
            c[l] = cn;
            const float hn = bfr(ov * tanh_np(cn));
            if (lane < HID) h_lds[l][lane] = hn;
            if (l == NLAY-1 && t == len-1) hout = hn;
        }
        x_lds[lane] = xn;
    }
    if (lane < HID) out[s * HID + lane] = hout;
}

extern "C" void kernel_launch(void* const* d_in, const int* in_sizes, int n_in,
                              void* d_out, int out_size, void* d_ws, size_t ws_size,
                              hipStream_t stream) {
    const float* emb     = (const float*)d_in[0];
    const int*   lengths = (const int*)  d_in[1];
    const float* Wih0    = (const float*)d_in[2];
    const float* Wihr    = (const float*)d_in[3];
    const float* Whh     = (const float*)d_in[4];
    const float* bih     = (const float*)d_in[5];
    const float* bhh     = (const float*)d_in[6];
    float* out = (float*)d_out;

    const size_t need = (size_t)BSZ * T2 * NG * sizeof(unsigned short);
    if (ws_size >= need) {
        unsigned short* pa = (unsigned short*)d_ws;
        proj0<<<2048, 256, 0, stream>>>(emb, lengths, Wih0, pa);
        lstm4_pipe<<<BSZ, 256, 0, stream>>>(lengths, pa, Wihr, Whh, bih, bhh, out);
    } else {
        lstm4_bf16np<<<BSZ, 64, 0, stream>>>(emb, lengths, Wih0, Wihr, Whh, bih, bhh, out);
    }
}

// Round 16
// 2050.194 us; speedup vs baseline: 1.2064x; 1.0287x over previous
//
#include <hip/hip_runtime.h>
#include <hip/hip_bf16.h>

#define HID 15
#define NG  60      // 4*HID
#define DIM 64
#define T2  2048
#define NLAY 4
#define BSZ 512
#define DG  8       // supersteps per barrier group (layer skew depth)
#define RS  16      // h-ring slots = 2*DG

// bf16 RNE rounding via compiler's __float2bfloat16 — PROVEN R15 (absmax
// 0.00390625, −240us vs bit-trick: HW cvt, shorter dependent chain).
__device__ __forceinline__ float bfr(float x) {
    __hip_bfloat16 h = __float2bfloat16(x);
    unsigned short u;
    __builtin_memcpy(&u, &h, 2);
    return __uint_as_float(((unsigned)u) << 16);
}
// one bf16-rounded multiply-accumulate term: acc = bf(acc + bf(a*b))
#define CH(acc, a, b) acc = bfr(acc + bfr((a) * (b)))

__device__ __forceinline__ float tanh_np(float z) {
    const float e = __expf(-2.0f * z);
    return bfr((1.0f - e) / (1.0f + e));
}
__device__ __forceinline__ float sig_np(float z) {
    const float e   = bfr(__expf(-z));
    const float den = bfr(1.0f + e);
    return bfr(1.0f / den);
}
__device__ __forceinline__ float b2f(unsigned b) {
    return __uint_as_float(b << 16);
}

// ============ Phase 1: layer-0 projection with dead-row load skip ============
// ~50% of rows have t >= len (never consumed). The liveness scan (wave-uniform,
// lengths L1-resident) skips them BEFORE loading — halves VMEM traffic and
// pipeline slots. Compute path identical to R13/R15 -> identical pa bytes.
__global__ __launch_bounds__(256, 1)
void proj0(const float* __restrict__ emb,
           const int*   __restrict__ lengths,
           const float* __restrict__ Wih0,
           unsigned short* __restrict__ pa)
{
    const int wave = threadIdx.x >> 6;
    const int lane = threadIdx.x & 63;
    const int g    = (lane < NG) ? lane : (NG - 1);

    __shared__ __align__(16) float xrow[4][2][64];

    float wx[DIM];
    #pragma unroll
    for (int q = 0; q < 16; ++q) {
        float4 w = *(const float4*)(Wih0 + g*DIM + 4*q);
        wx[4*q+0] = bfr(w.x); wx[4*q+1] = bfr(w.y);
        wx[4*q+2] = bfr(w.z); wx[4*q+3] = bfr(w.w);
    }

    const int npairs = (BSZ * T2) / 2;
    const int stride = gridDim.x * 4;

    // live(p): pair p = rows {2p, 2p+1} of seq b=2p/T2; t=2p mod T2 (even).
    // Pair is live iff t < len[b] (then row 2p is consumed; 2p+1 iff t+1<len).
    #define LIVE(p, tt, bb) (((tt) = (2*(p)) & (T2-1)), ((bb) = (2*(p)) >> 11), \
                             ((tt) < lengths[(bb)]))

    int t_, b_;
    int r = blockIdx.x * 4 + wave;
    while (r < npairs && !LIVE(r, t_, b_)) r += stride;   // first live pair

    float xr0 = 0.0f, xr1 = 0.0f;
    if (r < npairs) {                        // prime pipeline
        xr0 = emb[(size_t)(2*r)     * DIM + lane];
        xr1 = emb[(size_t)(2*r + 1) * DIM + lane];
    }

    while (r < npairs) {
        int rn = r + stride;                 // scan to next live pair (no loads)
        while (rn < npairs && !LIVE(rn, t_, b_)) rn += stride;

        float xn0 = 0.0f, xn1 = 0.0f;
        if (rn < npairs) {                   // prefetch next live pair
            xn0 = emb[(size_t)(2*rn)     * DIM + lane];
            xn1 = emb[(size_t)(2*rn + 1) * DIM + lane];
        }

        // compute current pair (known live)
        const int t   = (2*r) & (T2 - 1);
        const int len = lengths[(2*r) >> 11];

        xrow[wave][0][lane] = bfr(xr0);      // in-wave write->read (lgkmcnt)
        xrow[wave][1][lane] = bfr(xr1);
        const float4* xv0 = (const float4*)xrow[wave][0];
        const float4* xv1 = (const float4*)xrow[wave][1];
        float a0 = 0.0f, a1 = 0.0f;          // two independent chains
        #pragma unroll
        for (int q = 0; q < 16; ++q) {
            float4 u = xv0[q]; float4 v = xv1[q];
            CH(a0, u.x, wx[4*q+0]); CH(a1, v.x, wx[4*q+0]);
            CH(a0, u.y, wx[4*q+1]); CH(a1, v.y, wx[4*q+1]);
            CH(a0, u.z, wx[4*q+2]); CH(a1, v.z, wx[4*q+2]);
            CH(a0, u.w, wx[4*q+3]); CH(a1, v.w, wx[4*q+3]);
        }
        if (lane < NG) {
            pa[(size_t)(2*r) * NG + g] = (unsigned short)(__float_as_uint(a0) >> 16);
            if (t + 1 < len)
                pa[(size_t)(2*r + 1) * NG + g] = (unsigned short)(__float_as_uint(a1) >> 16);
        }
        r = rn; xr0 = xn0; xr1 = xn1;
    }
    #undef LIVE
}

// ====== Phase 2: deep-ring layer pipeline (R13/R15 structure) ======
// Single-exp activation: e = exp(tg ? -2z : -z) computed ONCE; both exact
// per-gate tails + select. Per-lane op sequence unchanged -> bit-identical.
__global__ __launch_bounds__(256, 1)
void lstm4_pipe(const int* __restrict__ lengths,
                const unsigned short* __restrict__ pa,
                const float* __restrict__ Wihr,
                const float* __restrict__ Whh,
                const float* __restrict__ bih,
                const float* __restrict__ bhh,
                float* __restrict__ out)
{
    const int s    = blockIdx.x;
    const int wave = threadIdx.x >> 6;     // = layer index l
    const int lane = threadIdx.x & 63;
    const int g    = (lane < NG) ? lane : (NG - 1);

    __shared__ __align__(16) float ring[NLAY-1][RS][16];   // layers 0..2 publish

    const int l = wave;
    float wr[16], wi[16];
    #pragma unroll
    for (int j = 0; j < HID; ++j) wr[j] = bfr(Whh[(l*NG + g)*HID + j]);
    wr[15] = 0.0f;
    if (l > 0) {
        #pragma unroll
        for (int j = 0; j < HID; ++j) wi[j] = bfr(Wihr[((l-1)*NG + g)*HID + j]);
        wi[15] = 0.0f;
    } else {
        #pragma unroll
        for (int j = 0; j < 16; ++j) wi[j] = 0.0f;
    }
    const float bias_ = bfr(bfr(bih[l*NG + g]) + bfr(bhh[l*NG + g]));

    int len = lengths[s];
    len = len < 1 ? 1 : (len > T2 ? T2 : len);
    const unsigned short* pas = pa + (size_t)s * T2 * NG;

    float c_ = 0.0f;
    float hs[HID];
    #pragma unroll
    for (int j = 0; j < HID; ++j) hs[j] = 0.0f;

    // pa group-prefetch, double-buffered 8-deep (wave 0 only)
    unsigned pan_c[DG], pan_n[DG];
    if (l == 0) {
        #pragma unroll
        for (int d = 0; d < DG; ++d) {
            const int tt = (d < len) ? d : (len - 1);
            pan_n[d] = pas[(size_t)tt * NG + g];
        }
    }

    const bool tg = (lane >= 30 && lane < 45);
    const int ngrp = (len + DG - 1) / DG;    // active groups per wave
    const int G    = ngrp + NLAY - 1;

    for (int grp = 0; grp < G; ++grp) {
        const int myg = grp - l;
        if (myg >= 0 && myg < ngrp) {        // wave-uniform
            const int t0 = myg * DG;

            if (l == 0) {                    // rotate buffers, prefetch next 8
                #pragma unroll
                for (int d = 0; d < DG; ++d) pan_c[d] = pan_n[d];
                #pragma unroll
                for (int d = 0; d < DG; ++d) {
                    int tt = t0 + DG + d; tt = (tt < len) ? tt : (len - 1);
                    pan_n[d] = pas[(size_t)tt * NG + g];
                }
            }

            #pragma unroll
            for (int d = 0; d < DG; ++d) {   // 8 supersteps, NO barrier inside
                const int t = t0 + d;
                if (t < len) {               // wave-uniform
                    float a_in = 0.0f, a_rec = 0.0f;
                    float hv[16];

                    if (l > 0) {             // issue LDS reads early
                        const float4* hp = (const float4*)ring[l-1][t & (RS-1)];
                        *(float4*)&hv[0]  = hp[0]; *(float4*)&hv[4]  = hp[1];
                        *(float4*)&hv[8]  = hp[2]; *(float4*)&hv[12] = hp[3];
                    }

                    #pragma unroll
                    for (int j = 0; j < HID; ++j) CH(a_rec, hs[j], wr[j]);

                    if (l == 0) {
                        a_in = b2f(pan_c[d]);
                    } else {
                        #pragma unroll
                        for (int j = 0; j < HID; ++j) CH(a_in, hv[j], wi[j]);
                    }

                    const float z = bfr(bfr(a_in + a_rec) + bias_);

                    // single-exp activation; exact per-gate op sequences
                    const float arg = tg ? (-2.0f * z) : (-z);
                    const float e   = __expf(arg);
                    const float es  = bfr(e);               // sig tail
                    const float dn  = bfr(1.0f + es);
                    const float rsg = bfr(1.0f / dn);
                    const float rth = bfr((1.0f - e) / (1.0f + e));  // tanh tail
                    const float a   = tg ? rth : rsg;

                    const float fv = __shfl(a, (lane + 15) & 63);
                    const float gv = __shfl(a, (lane + 30) & 63);
                    const float ov = __shfl(a, (lane + 45) & 63);

                    const float cn = bfr(bfr(fv * c_) + bfr(a * gv));
                    c_ = cn;
                    const float hn = bfr(ov * tanh_np(cn));

                    #pragma unroll
                    for (int j = 0; j < HID; ++j)
                        hs[j] = __uint_as_float(__builtin_amdgcn_readlane(__float_as_uint(hn), j));

                    if (l < NLAY - 1 && lane < HID) ring[l][t & (RS-1)][lane] = hn;
                    if (l == NLAY - 1 && t == len - 1 && lane < HID)
                        out[s * HID + lane] = hn;
                }
            }
        }
        __syncthreads();                     // one barrier per group
    }
}

// ============ Fallback (round-6, passing): used if ws too small ============
__global__ __launch_bounds__(64, 1)
void lstm4_bf16np(const float* __restrict__ emb,
                  const int*   __restrict__ lengths,
                  const float* __restrict__ Wih0,
                  const float* __restrict__ Wihr,
                  const float* __restrict__ Whh,
                  const float* __restrict__ bih,
                  const float* __restrict__ bhh,
                  float* __restrict__ out)
{
    const int s    = blockIdx.x;
    const int lane = threadIdx.x;
    const int g    = (lane < NG) ? lane : (NG - 1);

    __shared__ __align__(16) float x_lds[DIM];
    __shared__ __align__(16) float h_lds[NLAY][16];

    float wx[DIM];
    #pragma unroll
    for (int q = 0; q < DIM/4; ++q) {
        float4 w = *(const float4*)(Wih0 + g*DIM + 4*q);
        wx[4*q+0] = bfr(w.x); wx[4*q+1] = bfr(w.y);
        wx[4*q+2] = bfr(w.z); wx[4*q+3] = bfr(w.w);
    }
    float wr[NLAY][16]; float wi[NLAY-1][16]; float bias[NLAY];
    #pragma unroll
    for (int l = 0; l < NLAY; ++l) {
        #pragma unroll
        for (int j = 0; j < HID; ++j) wr[l][j] = bfr(Whh[(l*NG + g)*HID + j]);
        wr[l][15] = 0.0f;
        bias[l] = bfr(bfr(bih[l*NG + g]) + bfr(bhh[l*NG + g]));
    }
    #pragma unroll
    for (int l = 0; l < NLAY-1; ++l) {
        #pragma unroll
        for (int j = 0; j < HID; ++j) wi[l][j] = bfr(Wihr[(l*NG + g)*HID + j]);
        wi[l][15] = 0.0f;
    }
    if (lane < 16) {
        #pragma unroll
        for (int l = 0; l < NLAY; ++l) h_lds[l][lane] = 0.0f;
    }
    float c[NLAY] = {0.0f, 0.0f, 0.0f, 0.0f};
    int len = lengths[s];
    len = len < 1 ? 1 : (len > T2 ? T2 : len);
    const float* xb = emb + (size_t)s * T2 * DIM;
    x_lds[lane] = bfr(xb[lane]);
    __syncthreads();
    const bool tg = (lane >= 30 && lane < 45);
    const float4* x4 = (const float4*)x_lds;
    float hout = 0.0f;
    for (int t = 0; t < len; ++t) {
        const int tn = (t + 1 < len) ? (t + 1) : t;
        const float xn = bfr(xb[(size_t)tn * DIM + lane]);
        #pragma unroll
        for (int l = 0; l < NLAY; ++l) {
            float a_in = 0.0f;
            if (l == 0) {
                #pragma unroll
                for (int q = 0; q < 16; ++q) {
                    float4 v = x4[q];
                    CH(a_in, v.x, wx[4*q+0]); CH(a_in, v.y, wx[4*q+1]);
                    CH(a_in, v.z, wx[4*q+2]); CH(a_in, v.w, wx[4*q+3]);
                }
            } else {
                const float4* hp = (const float4*)h_lds[l-1];
                float hv[16];
                *(float4*)&hv[0]  = hp[0]; *(float4*)&hv[4]  = hp[1];
                *(float4*)&hv[8]  = hp[2]; *(float4*)&hv[12] = hp[3];
                #pragma unroll
                for (int j = 0; j < HID; ++j) CH(a_in, hv[j], wi[l-1][j]);
            }
            float a_rec = 0.0f;
            {
                const float4* hc = (const float4*)h_lds[l];
                float hv[16];
                *(float4*)&hv[0]  = hc[0]; *(float4*)&hv[4]  = hc[1];
                *(float4*)&hv[8]  = hc[2]; *(float4*)&hv[12] = hc[3];
                #pragma unroll
                for (int j = 0; j < HID; ++j) CH(a_rec, hv[j], wr[l][j]);
            }
            const float z = bfr(bfr(a_in + a_rec) + bias[l]);
            const float a = tg ? tanh_np(z) : sig_np(z);
            const float fv = __shfl(a, (lane + 15) & 63);
            const float gv = __shfl(a, (lane + 30) & 63);
            const float ov = __shfl(a, (lane + 45) & 63);
            const float cn = bfr(bfr(fv * c[l]) + bfr(a * gv));
            c[l] = cn;
            const float hn = bfr(ov * tanh_np(cn));
            if (lane < HID) h_lds[l][lane] = hn;
            if (l == NLAY-1 && t == len-1) hout = hn;
        }
        x_lds[lane] = xn;
    }
    if (lane < HID) out[s * HID + lane] = hout;
}

extern "C" void kernel_launch(void* const* d_in, const int* in_sizes, int n_in,
                              void* d_out, int out_size, void* d_ws, size_t ws_size,
                              hipStream_t stream) {
    const float* emb     = (const float*)d_in[0];
    const int*   lengths = (const int*)  d_in[1];
    const float* Wih0    = (const float*)d_in[2];
    const float* Wihr    = (const float*)d_in[3];
    const float* Whh     = (const float*)d_in[4];
    const float* bih     = (const float*)d_in[5];
    const float* bhh     = (const float*)d_in[6];
    float* out = (float*)d_out;

    const size_t need = (size_t)BSZ * T2 * NG * sizeof(unsigned short);
    if (ws_size >= need) {
        unsigned short* pa = (unsigned short*)d_ws;
        proj0<<<2048, 256, 0, stream>>>(emb, lengths, Wih0, pa);
        lstm4_pipe<<<BSZ, 256, 0, stream>>>(lengths, pa, Wihr, Whh, bih, bhh, out);
    } else {
        lstm4_bf16np<<<BSZ, 64, 0, stream>>>(emb, lengths, Wih0, Wihr, Whh, bih, bhh, out);
    }
}